// Round 1
// baseline (181.351 us; speedup 1.0000x reference)
//
#include <hip/hip_runtime.h>
#include <hip/hip_fp16.h>

#define N_NODES 10000
#define BATCH   8
#define IN_SZ   64
#define UNITS   64
#define ROW_U   256            // uints per f16 row (512 f16 = 4 stripes of 64)
#define RCAP    96             // fixed per-row edge capacity (P(deg>96) ~ 1e-18)
#define STR     (N_NODES * 64) // uints per stripe (640,000)

typedef unsigned int uint;
typedef unsigned short ushort;
typedef __attribute__((ext_vector_type(8))) _Float16 half8;
typedef __attribute__((ext_vector_type(4))) float float4v;
typedef __attribute__((ext_vector_type(2))) float float2v;

// ---- numeric helpers -------------------------------------------------------
// Edge values stay bf16-packed (high 16 bits ARE the fp32 bits -> SALU decode).
__device__ inline uint f2bf_bits(float f) {
    uint u = __float_as_uint(f);
    uint r = ((u >> 16) & 1u) + 0x7FFFu;
    return (u + r) >> 16;
}
// x tensors now stored as packed fp16 (RNE): 10-bit mantissa > bf16's 8,
// and enables v_fma_mix_f32 (f32 += f32 * f16 with op_sel) in the spmm loop.
__device__ inline uint pack2h(float a, float b) {
    return (uint)__half_as_ushort(__float2half(a)) |
           ((uint)__half_as_ushort(__float2half(b)) << 16);
}
__device__ inline float h_lo(uint u) {
    return __half2float(__ushort_as_half((ushort)(u & 0xFFFFu)));
}
__device__ inline float h_hi(uint u) {
    return __half2float(__ushort_as_half((ushort)(u >> 16)));
}

// ---------------------------------------------------------------------------
// k_transpose_scatter: transpose in[b,n,i] fp32 -> x0 stripe layout fp16;
// scatter COO edges into fixed 96-slot row buckets as PACKED 4-byte records:
// low 14 bits = col, high 16 bits = val as bf16 (bit pattern of fp32>>16).
// ---------------------------------------------------------------------------
__global__ __launch_bounds__(256) void k_transpose_scatter(
    const float2v* __restrict__ in2, uint* __restrict__ x0,
    const int* __restrict__ rows, const int* __restrict__ cols,
    const float* __restrict__ vals, int* __restrict__ cursor,
    uint* __restrict__ edges, int nnz) {
    int gid = blockIdx.x * 256 + threadIdx.x;      // 2,560,000 total
    if (gid < nnz) {
        int r   = rows[gid];
        int pos = r * RCAP + atomicAdd(&cursor[r], 1);
        edges[pos] = (uint)cols[gid] | (f2bf_bits(vals[gid]) << 16);
    }
    int n  = gid >> 8;          // node
    int b  = (gid >> 5) & 7;    // batch
    int iu = gid & 31;
    float2v v = __builtin_nontemporal_load(&in2[(size_t)b * (N_NODES * 32) +
                                                (size_t)n * 32 + iu]);
    int q = (gid >> 6) & 3;     // stripe
    x0[(size_t)q * STR + (size_t)n * 64 + (gid & 63)] = pack2h(v.x, v.y);
}

// ---------------------------------------------------------------------------
// k_spmm: one WAVE per (row, stripe); lane owns one uint (2 fp16 cols).
// r13 PMC: VALUBusy 56%, FETCH near-ideal, HBM 5% -> VALU-issue-bound.
// This round:
//  - fp16 x storage -> inner loop is 2x v_fma_mix_f32 per uint per edge
//    (replaces 2 unpack + 2 fmac on bf16): ~2x fewer VALU ops where bound.
//  - XCD-pinned stripes: blockIdx swizzle puts stripe q only on XCDs
//    {2q,2q+1}; per-XCD gather working set 2.56 MB < 4 MB L2 (was 10.2 MB).
// ---------------------------------------------------------------------------
__global__ __launch_bounds__(256) void k_spmm(const int* __restrict__ cursor,
                                              const uint* __restrict__ edges,
                                              const uint* __restrict__ xin,
                                              uint* __restrict__ xout,
                                              const uint* __restrict__ xsub,
                                              float scale) {
    int L    = blockIdx.x;              // 10000 blocks, dispatch ~round-robin
    int q    = (L & 7) >> 1;            // stripe pinned to XCD pair {2q,2q+1}
    int rb   = ((L >> 3) << 1) | (L & 1);   // 0..2499, bijective per stripe
    int wave = threadIdx.x >> 6;
    uint lane = threadIdx.x & 63;
    int row  = rb * 4 + wave;

    const uint* xq = xin + (size_t)q * STR;
    int base = row * RCAP;
    int cnt  = __builtin_amdgcn_readfirstlane(cursor[row]);

    float a0 = 0.f, a1 = 0.f;

    int full_end = base + (cnt & ~7);
    int e = base;
    for (; e < full_end; e += 8) {
        uint ep[8];
#pragma unroll
        for (int j = 0; j < 8; ++j) ep[j] = edges[e + j];   // uniform -> s_load
        uint x[8];
#pragma unroll
        for (int j = 0; j < 8; ++j)
            x[j] = xq[(ep[j] & 0x3FFFu) * 64u + lane];      // SALU idx, saddr
#pragma unroll
        for (int j = 0; j < 8; ++j) {
            float vj = __uint_as_float(ep[j] & 0xFFFF0000u); // SALU: bf16->f32
            a0 += vj * h_lo(x[j]);                           // v_fma_mix_f32
            a1 += vj * h_hi(x[j]);                           // v_fma_mix_f32
        }
    }
    int rem = cnt & 7;
    if (rem) {
        uint ep[8];
#pragma unroll
        for (int j = 0; j < 8; ++j) ep[j] = edges[e + j];
        uint x[8];
#pragma unroll
        for (int j = 0; j < 8; ++j) {
            uint c = ep[j] & 0x3FFFu;
            if (c > N_NODES - 1) c = N_NODES - 1;            // s_min (poison)
            x[j] = xq[c * 64u + lane];
        }
#pragma unroll
        for (int j = 0; j < 8; ++j) {
            float vj = (j < rem) ? __uint_as_float(ep[j] & 0xFFFF0000u) : 0.f;
            a0 += vj * h_lo(x[j]);
            a1 += vj * h_hi(x[j]);
        }
    }

    float o0 = scale * a0, o1 = scale * a1;
    if (xsub) {
        uint sx = __builtin_nontemporal_load(
            &xsub[(size_t)q * STR + (size_t)row * 64 + lane]);
        o0 -= h_lo(sx);
        o1 -= h_hi(sx);
    }
    __builtin_nontemporal_store(pack2h(o0, o1),
        &xout[(size_t)q * STR + (size_t)row * 64 + lane]);
}

// ---------------------------------------------------------------------------
// k_combine (MFMA f16): out[b,n,u] = bias[u] + sum_k A[(b,n), k] * Wp[k, u].
// 1-D grid 157*8; b = L&7 so stripe q=b>>1 reads stay on XCD pair {2q,2q+1}
// (matches spmm write locality).
// ---------------------------------------------------------------------------
__global__ __launch_bounds__(256) void k_combine(const uint* __restrict__ x0,
                                                 const uint* __restrict__ x1,
                                                 const uint* __restrict__ x2,
                                                 const float* __restrict__ W,
                                                 const float* __restrict__ bias,
                                                 float* __restrict__ out) {
    __shared__ ushort sWt[64][200];    // [u][k] f16, pad 192->200 (25.6 KB)
    int t = threadIdx.x;
    for (int e = t; e < 192 * 64; e += 256) {
        int f = e >> 6;                // fan_in row = i*3 + m
        int u = e & 63;
        int i = f / 3;
        int m = f - 3 * i;
        sWt[u][m * 64 + i] = __half_as_ushort(__float2half(W[e]));
    }
    __syncthreads();

    int wave = t >> 6, lane = t & 63;
    int mrow = lane & 15, quad = lane >> 4;
    int L    = blockIdx.x;
    int b    = L & 7;                  // XCD-pinned batch -> stripe b>>1
    int n0   = (L >> 3) * 64 + wave * 16;

    const uint* xs[3] = {x0, x1, x2};
    int an = n0 + mrow;
    if (an > N_NODES - 1) an = N_NODES - 1;    // clamp tail reads

    half8 af[6];
#pragma unroll
    for (int kb = 0; kb < 6; ++kb) {
        int mat = kb >> 1;
        int c_u = b * 32 + (kb & 1) * 16 + quad * 4;      // column uint index
        int q   = c_u >> 6;                               // = b>>1
        af[kb] = __builtin_nontemporal_load(
            (const half8*)(xs[mat] + (size_t)q * STR + (size_t)an * 64 +
                           (c_u & 63)));
    }

    float4v acc[4];
#pragma unroll
    for (int ut = 0; ut < 4; ++ut) acc[ut] = (float4v){0.f, 0.f, 0.f, 0.f};

#pragma unroll
    for (int kb = 0; kb < 6; ++kb)
#pragma unroll
        for (int ut = 0; ut < 4; ++ut)
            acc[ut] = __builtin_amdgcn_mfma_f32_16x16x32_f16(
                af[kb],
                *(const half8*)&sWt[ut * 16 + mrow][kb * 32 + quad * 8],
                acc[ut], 0, 0, 0);

#pragma unroll
    for (int ut = 0; ut < 4; ++ut) {
        float bv = bias[ut * 16 + mrow];
        int u = ut * 16 + mrow;
#pragma unroll
        for (int r = 0; r < 4; ++r) {
            int n = n0 + quad * 4 + r;
            if (n < N_NODES)
                __builtin_nontemporal_store(acc[ut][r] + bv,
                    &out[((size_t)b * N_NODES + n) * UNITS + u]);
        }
    }
}

// ---------------------------------------------------------------------------
extern "C" void kernel_launch(void* const* d_in, const int* in_sizes, int n_in,
                              void* d_out, int out_size, void* d_ws, size_t ws_size,
                              hipStream_t stream) {
    const float* inputs = (const float*)d_in[0];
    const int*   rows   = (const int*)d_in[1];
    const int*   cols   = (const int*)d_in[2];
    const float* vals   = (const float*)d_in[3];
    const float* W      = (const float*)d_in[4];
    const float* bias   = (const float*)d_in[5];
    float*       out    = (float*)d_out;
    int nnz = in_sizes[1];

    char* p = (char*)d_ws;
    auto alloc = [&](size_t bytes) {
        char* r = p;
        p += (bytes + 255) & ~(size_t)255;
        return r;
    };
    uint* x0     = (uint*)alloc(sizeof(uint) * (size_t)N_NODES * ROW_U);
    uint* x1     = (uint*)alloc(sizeof(uint) * (size_t)N_NODES * ROW_U);
    uint* x2     = (uint*)alloc(sizeof(uint) * (size_t)N_NODES * ROW_U);
    int*  cursor = (int*)alloc(sizeof(int) * N_NODES);
    uint* edges  = (uint*)alloc(sizeof(uint) * (size_t)N_NODES * RCAP);

    (void)hipMemsetAsync(cursor, 0, sizeof(int) * N_NODES, stream);
    k_transpose_scatter<<<N_NODES, 256, 0, stream>>>((const float2v*)inputs, x0,
                                                     rows, cols, vals, cursor,
                                                     edges, nnz);
    k_spmm<<<N_NODES, 256, 0, stream>>>(cursor, edges, x0, x1, nullptr, 1.0f);
    k_spmm<<<N_NODES, 256, 0, stream>>>(cursor, edges, x1, x2, x0, 2.0f);
    k_combine<<<157 * 8, 256, 0, stream>>>(x0, x1, x2, W, bias, out);
}